// Round 1
// baseline (504.935 us; speedup 1.0000x reference)
//
#include <hip/hip_runtime.h>
#include <stdint.h>

// WMSA (Swin shifted-window attention), fused single kernel per window.
// B=4, H=W=256, C=192, heads=6, head_dim=32, WS=8, SHIFT=4.
// 4096 windows, one workgroup (256 thr / 4 waves) each, 32x32x16 bf16 MFMA.

typedef __bf16 bf16x8 __attribute__((ext_vector_type(8)));
typedef float f32x16 __attribute__((ext_vector_type(16)));
typedef unsigned int uint2v __attribute__((ext_vector_type(2)));

#define MFMA32 __builtin_amdgcn_mfma_f32_32x32x16_bf16

#define WOUT_OFF 110592   // ushort offset of packed w_out in ws
#define BIAS_OFF 147456   // ushort offset of bias table in ws
#define SIM_SCALE 0.1767766952966369f

static __device__ __forceinline__ unsigned short f2bf(float f) {
  return __builtin_bit_cast(unsigned short, (__bf16)f);
}
static __device__ __forceinline__ float bf2f(unsigned short u) {
  unsigned int x = ((unsigned int)u) << 16;
  return __builtin_bit_cast(float, x);
}
static __device__ __forceinline__ unsigned int pk2(float a, float b) {
  return (unsigned int)f2bf(a) | ((unsigned int)f2bf(b) << 16);
}
static __device__ __forceinline__ bf16x8 mk8(unsigned int a, unsigned int b,
                                             unsigned int c, unsigned int d) {
  uint4 t; t.x = a; t.y = b; t.z = c; t.w = d;
  return __builtin_bit_cast(bf16x8, t);
}

// ---------------- pre-pack kernel ----------------
// ws layout (ushort units):
//   [0, 110592)              w_qkv packed: slot (ks*18+nt)*64+lane, 8 bf16:
//                            element j = w_qkv[(ks*16+(lane>>5)*8+j)*576 + nt*32+(lane&31)]
//   [110592, 147456)         w_out packed: slot (ks*6+oct)*64+lane, 8 bf16:
//                            element j = w_out[(ks*16+(lane>>5)*8+j)*192 + oct*32+(lane&31)]
//   [147456, 172032)         bias table [6][64][64]: rel_pos[h][pr-qr+7][pc-qc+7]
__global__ void pack_kernel(const float* __restrict__ wqkv,
                            const float* __restrict__ wout,
                            const float* __restrict__ relpos,
                            unsigned short* __restrict__ ws) {
  int tid = blockIdx.x * 256 + threadIdx.x;
  if (tid < 13824) {
    int lane = tid & 63, t = tid >> 6;
    int ks = t / 18, nt = t - ks * 18;
    int n = nt * 32 + (lane & 31);
    int c0 = ks * 16 + (lane >> 5) * 8;
    unsigned short v[8];
#pragma unroll
    for (int j = 0; j < 8; ++j) v[j] = f2bf(wqkv[(size_t)(c0 + j) * 576 + n]);
    ushort4 a; a.x = v[0]; a.y = v[1]; a.z = v[2]; a.w = v[3];
    ushort4 bq; bq.x = v[4]; bq.y = v[5]; bq.z = v[6]; bq.w = v[7];
    *(ushort4*)(ws + (size_t)tid * 8) = a;
    *(ushort4*)(ws + (size_t)tid * 8 + 4) = bq;
  } else if (tid < 13824 + 4608) {
    int id = tid - 13824;
    int lane = id & 63, t = id >> 6;
    int ks = t / 6, oct = t - ks * 6;
    int oc = oct * 32 + (lane & 31);
    int c0 = ks * 16 + (lane >> 5) * 8;
    unsigned short v[8];
#pragma unroll
    for (int j = 0; j < 8; ++j) v[j] = f2bf(wout[(size_t)(c0 + j) * 192 + oc]);
    ushort4 a; a.x = v[0]; a.y = v[1]; a.z = v[2]; a.w = v[3];
    ushort4 bq; bq.x = v[4]; bq.y = v[5]; bq.z = v[6]; bq.w = v[7];
    *(ushort4*)(ws + WOUT_OFF + (size_t)id * 8) = a;
    *(ushort4*)(ws + WOUT_OFF + (size_t)id * 8 + 4) = bq;
  } else if (tid < 13824 + 4608 + 384) {
    int id = tid - 18432;
    int h = id >> 6, p = id & 63;
    int pr = p >> 3, pc = p & 7;
#pragma unroll
    for (int q4 = 0; q4 < 16; ++q4) {
      unsigned short v[4];
#pragma unroll
      for (int j = 0; j < 4; ++j) {
        int q = q4 * 4 + j;
        int r0 = pr - (q >> 3) + 7;
        int r1 = pc - (q & 7) + 7;
        v[j] = f2bf(relpos[h * 225 + r0 * 15 + r1]);
      }
      ushort4 o; o.x = v[0]; o.y = v[1]; o.z = v[2]; o.w = v[3];
      *(ushort4*)(ws + BIAS_OFF + (size_t)(h * 64 + p) * 64 + q4 * 4) = o;
    }
  }
}

// ---------------- main fused kernel ----------------
// LDS (72 KiB total, all rows XOR-swizzled with ((row&7)<<4) on the byte offset):
//   [0,     24576)  Q [64 tok][192 ch] bf16   (later reused as attn-out [64][192])
//   [24576, 49152)  K [64 tok][192 ch] bf16
//   [49152, 73728)  V^T [6 h][32 d][64 tok] bf16
__global__ __launch_bounds__(256, 2)
void wmsa_kernel(const float* __restrict__ x, const float* __restrict__ bqkv,
                 const float* __restrict__ bout, const unsigned short* __restrict__ ws,
                 float* __restrict__ out) {
  __shared__ __align__(16) unsigned char smem[73728];

  const int tidx = threadIdx.x;
  const int wid = tidx >> 6, lane = tidx & 63;
  const int lo5 = lane & 31, hi = lane >> 5;
  const int bid = blockIdx.x;
  const int b = bid >> 10, widx = bid & 1023;
  const int wh = widx >> 5, ww = widx & 31;

  const int mt = wid & 1;            // token half (m-tile) this wave owns
  const int ntbase = (wid >> 1) * 9; // 9 qkv-column tiles per wave

  // per-lane token (for x loads, QKV writes, out-proj A reads/stores)
  const int m = mt * 32 + lo5;
  const int gh0 = (wh * 8 + (m >> 3) + 4) & 255;
  const int gw0 = (ww * 8 + (m & 7) + 4) & 255;
  const float* xtok = x + ((size_t)((b * 256 + gh0) * 256 + gw0)) * 192;

  const uint4* wqkvP = (const uint4*)ws;
  const uint4* woutP = (const uint4*)(ws + WOUT_OFF);
  const unsigned short* biasT = ws + BIAS_OFF;

  // ---- Phase A: QKV GEMM, swapped: D[n][m] = sum_c w[c][n] * x[m][c] ----
  f32x16 acc[9] = {};
#pragma unroll
  for (int ks = 0; ks < 12; ++ks) {
    const float4 xa = *(const float4*)(xtok + ks * 16 + hi * 8);
    const float4 xb = *(const float4*)(xtok + ks * 16 + hi * 8 + 4);
    const bf16x8 xf = mk8(pk2(xa.x, xa.y), pk2(xa.z, xa.w),
                          pk2(xb.x, xb.y), pk2(xb.z, xb.w));
#pragma unroll
    for (int t = 0; t < 9; ++t) {
      const uint4 w = wqkvP[(size_t)((ks * 18 + ntbase + t) * 64 + lane)];
      acc[t] = MFMA32(__builtin_bit_cast(bf16x8, w), xf, acc[t], 0, 0, 0);
    }
  }

  // ---- Phase B: +bias, convert, scatter to Q/K/V LDS ----
#pragma unroll
  for (int t = 0; t < 9; ++t) {
    const int nt = ntbase + t;
    if (nt < 12) {  // Q or K: lane holds fixed token, 4-consecutive cols per group
      unsigned char* base = smem + (nt < 6 ? 0 : 24576);
      const int col0 = (nt < 6 ? nt : nt - 6) * 32;
#pragma unroll
      for (int g = 0; g < 4; ++g) {
        const float4 bq = *(const float4*)(bqkv + nt * 32 + 8 * g + 4 * hi);
        const float bqa[4] = {bq.x, bq.y, bq.z, bq.w};
        const int c0 = col0 + 8 * g + 4 * hi;
        ushort4 wv;
        wv.x = f2bf(acc[t][4 * g + 0] + bqa[0]);
        wv.y = f2bf(acc[t][4 * g + 1] + bqa[1]);
        wv.z = f2bf(acc[t][4 * g + 2] + bqa[2]);
        wv.w = f2bf(acc[t][4 * g + 3] + bqa[3]);
        *(ushort4*)(base + m * 384 + ((c0 * 2) ^ ((m & 7) << 4))) = wv;
      }
    } else {  // V: store transposed [h][d][tok]
      const int h = nt - 12;
#pragma unroll
      for (int g = 0; g < 4; ++g) {
        const float4 bq = *(const float4*)(bqkv + nt * 32 + 8 * g + 4 * hi);
        const float bqa[4] = {bq.x, bq.y, bq.z, bq.w};
#pragma unroll
        for (int j = 0; j < 4; ++j) {
          const int d = 8 * g + 4 * hi + j;
          *(unsigned short*)(smem + 49152 + h * 4096 + d * 128 +
                             ((m * 2) ^ ((d & 7) << 4))) =
              f2bf(acc[t][4 * g + j] + bqa[j]);
        }
      }
    }
  }
  __syncthreads();

  // ---- Phase C: attention, 3 (head, query-half) units per wave ----
  const bool lastRow = (wh == 31), lastCol = (ww == 31);
  f32x16 oacc[3];
  float oscale[3];
#pragma unroll
  for (int u = 0; u < 3; ++u) {
    const int idx = wid * 3 + u;
    const int h = idx >> 1, ph = idx & 1;
    const int p = ph * 32 + lo5;  // this lane's query token
    const int swz = (lo5 & 7) << 4;

    // Q fragments (B operand of swapped sim), one per 16-dim k-step
    const bf16x8 qf0 = *(const bf16x8*)(smem + p * 384 + ((h * 64 + 0 + hi * 16) ^ swz));
    const bf16x8 qf1 = *(const bf16x8*)(smem + p * 384 + ((h * 64 + 32 + hi * 16) ^ swz));

    // sim^T[q][p] = K · Q^T  (two 32-row key tiles)
    f32x16 s0 = {}, s1 = {};
    {
      bf16x8 kf;
      kf = *(const bf16x8*)(smem + 24576 + lo5 * 384 + ((h * 64 + 0 + hi * 16) ^ swz));
      s0 = MFMA32(kf, qf0, s0, 0, 0, 0);
      kf = *(const bf16x8*)(smem + 24576 + lo5 * 384 + ((h * 64 + 32 + hi * 16) ^ swz));
      s0 = MFMA32(kf, qf1, s0, 0, 0, 0);
      kf = *(const bf16x8*)(smem + 24576 + (32 + lo5) * 384 + ((h * 64 + 0 + hi * 16) ^ swz));
      s1 = MFMA32(kf, qf0, s1, 0, 0, 0);
      kf = *(const bf16x8*)(smem + 24576 + (32 + lo5) * 384 + ((h * 64 + 32 + hi * 16) ^ swz));
      s1 = MFMA32(kf, qf1, s1, 0, 0, 0);
    }

    // scale + rel-pos bias + analytic shift mask
    float pv[2][16];
    const bool pA = (p >> 3) < 4;
    const bool mcol = lastCol && (((p & 7) < 4) != (hi == 0));
#pragma unroll
    for (int rt = 0; rt < 2; ++rt) {
      const bool mk = (lastRow && (pA != (rt == 0))) || mcol;
#pragma unroll
      for (int g = 0; g < 4; ++g) {
        const ushort4 bb = *(const ushort4*)(biasT + (size_t)(h * 64 + p) * 64 +
                                             rt * 32 + 8 * g + 4 * hi);
        const unsigned short bbv[4] = {bb.x, bb.y, bb.z, bb.w};
#pragma unroll
        for (int j = 0; j < 4; ++j) {
          const int r = 4 * g + j;
          const float v = (rt == 0 ? s0[r] : s1[r]) * SIM_SCALE + bf2f(bbv[j]);
          pv[rt][r] = mk ? -1e30f : v;
        }
      }
    }

    // softmax over keys: lane-local (16x2 values) + one cross-half exchange
    float mx = pv[0][0];
#pragma unroll
    for (int r = 1; r < 16; ++r) mx = fmaxf(mx, pv[0][r]);
#pragma unroll
    for (int r = 0; r < 16; ++r) mx = fmaxf(mx, pv[1][r]);
    mx = fmaxf(mx, __shfl_xor(mx, 32));
    float sum = 0.f;
#pragma unroll
    for (int rt = 0; rt < 2; ++rt)
#pragma unroll
      for (int r = 0; r < 16; ++r) {
        const float e = __expf(pv[rt][r] - mx);
        pv[rt][r] = e;
        sum += e;
      }
    sum += __shfl_xor(sum, 32);
    oscale[u] = __builtin_amdgcn_rcpf(sum);  // normalization deferred to epilogue

    // PV: out^T[d][p] = V^T · P^T ; P B-frags built in-register (cvt_pk + permlane32_swap)
    f32x16 oa = {};
#pragma unroll
    for (int rt = 0; rt < 2; ++rt) {
      const unsigned int W0 = pk2(pv[rt][0], pv[rt][1]);
      const unsigned int W1 = pk2(pv[rt][2], pv[rt][3]);
      const unsigned int W2 = pk2(pv[rt][4], pv[rt][5]);
      const unsigned int W3 = pk2(pv[rt][6], pv[rt][7]);
      const unsigned int W4 = pk2(pv[rt][8], pv[rt][9]);
      const unsigned int W5 = pk2(pv[rt][10], pv[rt][11]);
      const unsigned int W6 = pk2(pv[rt][12], pv[rt][13]);
      const unsigned int W7 = pk2(pv[rt][14], pv[rt][15]);
      const uint2v r0 = __builtin_amdgcn_permlane32_swap(W0, W2, false, false);
      const uint2v r1 = __builtin_amdgcn_permlane32_swap(W1, W3, false, false);
      const uint2v r2 = __builtin_amdgcn_permlane32_swap(W4, W6, false, false);
      const uint2v r3 = __builtin_amdgcn_permlane32_swap(W5, W7, false, false);
      const bf16x8 f0 = mk8(r0[0], r1[0], r0[1], r1[1]);
      const bf16x8 f1 = mk8(r2[0], r3[0], r2[1], r3[1]);
      const bf16x8 va = *(const bf16x8*)(smem + 49152 + h * 4096 + lo5 * 128 +
                                         (((rt * 2 + 0) * 32 + hi * 16) ^ swz));
      oa = MFMA32(va, f0, oa, 0, 0, 0);
      const bf16x8 vb = *(const bf16x8*)(smem + 49152 + h * 4096 + lo5 * 128 +
                                         (((rt * 2 + 1) * 32 + hi * 16) ^ swz));
      oa = MFMA32(vb, f1, oa, 0, 0, 0);
    }
    oacc[u] = oa;
  }
  __syncthreads();

  // ---- Phase D: write attention output over the (dead) Q region ----
#pragma unroll
  for (int u = 0; u < 3; ++u) {
    const int idx = wid * 3 + u;
    const int h = idx >> 1, ph = idx & 1;
    const int p = ph * 32 + lo5;
    const float sc = oscale[u];
#pragma unroll
    for (int g = 0; g < 4; ++g) {
      ushort4 wv;
      wv.x = f2bf(oacc[u][4 * g + 0] * sc);
      wv.y = f2bf(oacc[u][4 * g + 1] * sc);
      wv.z = f2bf(oacc[u][4 * g + 2] * sc);
      wv.w = f2bf(oacc[u][4 * g + 3] * sc);
      const int c0 = h * 32 + 8 * g + 4 * hi;
      *(ushort4*)(smem + p * 384 + ((c0 * 2) ^ ((p & 7) << 4))) = wv;
    }
  }
  __syncthreads();

  // ---- Phase E: out-projection + rolled store ----
  const int octb = (wid >> 1) * 3;
  f32x16 po[3] = {};
#pragma unroll
  for (int ks = 0; ks < 12; ++ks) {
    const bf16x8 af = *(const bf16x8*)(smem + (mt * 32 + lo5) * 384 +
                                       ((ks * 32 + hi * 16) ^ ((lo5 & 7) << 4)));
#pragma unroll
    for (int j = 0; j < 3; ++j) {
      const uint4 w = woutP[(size_t)((ks * 6 + octb + j) * 64 + lane)];
      po[j] = MFMA32(af, __builtin_bit_cast(bf16x8, w), po[j], 0, 0, 0);
    }
  }
#pragma unroll
  for (int j = 0; j < 3; ++j) {
    const int oc = (octb + j) * 32 + lo5;
    const float bo = bout[oc];
#pragma unroll
    for (int r = 0; r < 16; ++r) {
      const int tok = mt * 32 + (r & 3) + 8 * (r >> 2) + 4 * hi;
      const int gh = (wh * 8 + (tok >> 3) + 4) & 255;
      const int gw = (ww * 8 + (tok & 7) + 4) & 255;
      out[(size_t)((b * 256 + gh) * 256 + gw) * 192 + oc] = po[j][r] + bo;
    }
  }
}

extern "C" void kernel_launch(void* const* d_in, const int* in_sizes, int n_in,
                              void* d_out, int out_size, void* d_ws, size_t ws_size,
                              hipStream_t stream) {
  const float* x = (const float*)d_in[0];
  const float* wqkv = (const float*)d_in[1];
  const float* bqkv = (const float*)d_in[2];
  const float* relpos = (const float*)d_in[3];
  const float* wout = (const float*)d_in[4];
  const float* bout = (const float*)d_in[5];
  float* out = (float*)d_out;
  unsigned short* ws = (unsigned short*)d_ws;

  pack_kernel<<<dim3(74), dim3(256), 0, stream>>>(wqkv, wout, relpos, ws);
  wmsa_kernel<<<dim3(4096), dim3(256), 0, stream>>>(x, bqkv, bout, ws, out);
}